// Round 7
// baseline (36.734 us; speedup 1.0000x reference)
//
#include <hip/hip_runtime.h>
#include <hip/hip_bf16.h>

// Pooler ragged-mean via exclusive prefix sum.
// out[b,s,:] = (P[b, begin+w, :] - P[b, begin, :]) / w,  P[b,t,:] = sum_{t'<t} features[b,t',:]
// B=8, T=4096, D=256, S=1024, MAX_W=32. Empty spans -> 0.
//
// R7: kills the 4.1x gather duplication that held R2-R6 at ~14.5 us
// (L1-miss/MSHR throughput bound ~15 B/cyc/CU). Three streaming kernels:
//   K1: chunk sums (64 rows) per (b, chunk, d), f64 acc         [512 blocks]
//   K3: exclusive prefix per chunk (sums <64 chunk rows, L2-hot)
//       then writes P rows (f32) into d_ws                      [512 blocks]
//   K4: pool = diff of two P rows per span, nt-store            [2048 blocks]
// XCD pinning: batch b -> XCD b everywhere (4 MB = one XCD L2).

#define B_DIM 8
#define T_DIM 4096
#define D_DIM 256
#define S_DIM 1024
#define MAX_W 32
#define NXCD 8
#define CHUNK 64
#define NCHUNK (T_DIM / CHUNK)   // 64

typedef float vfloat4 __attribute__((ext_vector_type(4)));

__global__ __launch_bounds__(256) void chunk_sum_kernel(
    const float* __restrict__ f,       // [B, T, D]
    double*      __restrict__ csum)    // [B, NCHUNK, D]
{
    const int phys = blockIdx.x;             // 512
    const int b = phys & (NXCD - 1);         // XCD pin
    const int c = phys >> 3;                 // 0..63
    const int d = threadIdx.x;

    const float* p = f + ((size_t)b * T_DIM + (size_t)c * CHUNK) * D_DIM + d;
    double acc = 0.0;
    #pragma unroll 16
    for (int t = 0; t < CHUNK; ++t) acc += (double)p[(size_t)t * D_DIM];
    csum[((size_t)b * NCHUNK + c) * D_DIM + d] = acc;
}

__global__ __launch_bounds__(256) void cumsum_kernel(
    const float*  __restrict__ f,      // [B, T, D]
    const double* __restrict__ csum,   // [B, NCHUNK, D]
    float*        __restrict__ P)      // [B, T, D] exclusive prefix
{
    const int phys = blockIdx.x;             // 512
    const int b = phys & (NXCD - 1);
    const int c = phys >> 3;
    const int d = threadIdx.x;

    double pref = 0.0;
    const double* cs = csum + (size_t)b * NCHUNK * D_DIM + d;
    for (int cc = 0; cc < c; ++cc) pref += cs[(size_t)cc * D_DIM];

    const float* fp = f + ((size_t)b * T_DIM + (size_t)c * CHUNK) * D_DIM + d;
    float*       Pp = P + ((size_t)b * T_DIM + (size_t)c * CHUNK) * D_DIM + d;
    #pragma unroll 8
    for (int t = 0; t < CHUNK; ++t) {
        Pp[(size_t)t * D_DIM] = (float)pref;     // exclusive
        pref += (double)fp[(size_t)t * D_DIM];
    }
}

__global__ __launch_bounds__(256) void pool_diff_kernel(
    const float* __restrict__ P,       // [B, T, D]
    const int*   __restrict__ begins,  // [B, S]
    const int*   __restrict__ ends,    // [B, S]
    float*       __restrict__ out)     // [B, S, D]
{
    const int phys = blockIdx.x;
    const int lblk = (phys & (NXCD - 1)) * (2048 / NXCD) + (phys >> 3);

    const int span = lblk * 4 + (threadIdx.x >> 6);  // [0, B*S)
    const int lane = threadIdx.x & 63;
    const int b = span >> 10;                        // S_DIM = 1024

    int begin = begins[span];
    int end   = ends[span];
    begin = begin > 0 ? begin : 0;
    end   = end   > 0 ? end   : 0;
    end   = end   < T_DIM ? end : T_DIM;
    int w = end - begin;
    w = w < MAX_W ? w : MAX_W;

    vfloat4* outp = reinterpret_cast<vfloat4*>(out + (size_t)span * D_DIM) + lane;

    if (w <= 0) {
        vfloat4 z = {0.f, 0.f, 0.f, 0.f};
        __builtin_nontemporal_store(z, outp);
        return;
    }

    // begin <= 4063, begin + w <= min(end, begin+32) <= 4095 : both P rows exist.
    const vfloat4* Pb = reinterpret_cast<const vfloat4*>(
        P + ((size_t)b * T_DIM + begin) * D_DIM) + lane;
    const vfloat4* Pe = reinterpret_cast<const vfloat4*>(
        P + ((size_t)b * T_DIM + begin + w) * D_DIM) + lane;

    const vfloat4 vb = *Pb;
    const vfloat4 ve = *Pe;
    const float inv = 1.0f / (float)w;
    vfloat4 r = (ve - vb) * inv;
    __builtin_nontemporal_store(r, outp);
}

// ---- fallback (R5 path) if ws is too small for P + csum ----
__global__ __launch_bounds__(256) void pooler_direct_kernel(
    const float* __restrict__ features,
    const int*   __restrict__ begins,
    const int*   __restrict__ ends,
    float*       __restrict__ out)
{
    const int phys = blockIdx.x;
    const int lblk = (phys & (NXCD - 1)) * (2048 / NXCD) + (phys >> 3);
    const int span = lblk * 4 + (threadIdx.x >> 6);
    const int lane = threadIdx.x & 63;
    const int b = span >> 10;

    int begin = begins[span];
    int end   = ends[span];
    begin = begin > 0 ? begin : 0;
    end   = end   > 0 ? end   : 0;
    end   = end   < T_DIM ? end : T_DIM;
    int w = end - begin;
    w = w < MAX_W ? w : MAX_W;

    vfloat4* outp = reinterpret_cast<vfloat4*>(out + (size_t)span * D_DIM) + lane;
    if (w <= 0) {
        vfloat4 z = {0.f, 0.f, 0.f, 0.f};
        __builtin_nontemporal_store(z, outp);
        return;
    }
    const vfloat4* p = reinterpret_cast<const vfloat4*>(
        features + (size_t)b * T_DIM * D_DIM + (size_t)begin * D_DIM) + lane;
    vfloat4 acc = {0.f, 0.f, 0.f, 0.f};
    #pragma unroll 8
    for (int j = 0; j < w; ++j) acc += p[(size_t)j * (D_DIM / 4)];
    const float inv = 1.0f / (float)w;
    vfloat4 r = acc * inv;
    __builtin_nontemporal_store(r, outp);
}

extern "C" void kernel_launch(void* const* d_in, const int* in_sizes, int n_in,
                              void* d_out, int out_size, void* d_ws, size_t ws_size,
                              hipStream_t stream) {
    const float* features = (const float*)d_in[0];
    const int*   begins   = (const int*)d_in[1];
    const int*   ends     = (const int*)d_in[2];
    float*       out      = (float*)d_out;

    const size_t P_bytes    = (size_t)B_DIM * T_DIM * D_DIM * sizeof(float);   // 32 MB
    const size_t csum_bytes = (size_t)B_DIM * NCHUNK * D_DIM * sizeof(double); // 1 MB

    if (ws_size >= P_bytes + csum_bytes) {
        float*  P    = (float*)d_ws;
        double* csum = (double*)((char*)d_ws + P_bytes);

        chunk_sum_kernel<<<B_DIM * NCHUNK, 256, 0, stream>>>(features, csum);
        cumsum_kernel<<<B_DIM * NCHUNK, 256, 0, stream>>>(features, csum, P);
        pool_diff_kernel<<<(B_DIM * S_DIM) / 4, 256, 0, stream>>>(P, begins, ends, out);
    } else {
        pooler_direct_kernel<<<(B_DIM * S_DIM) / 4, 256, 0, stream>>>(
            features, begins, ends, out);
    }
}

// Round 8
// 23.025 us; speedup vs baseline: 1.5954x; 1.5954x over previous
//
#include <hip/hip_runtime.h>
#include <hip/hip_bf16.h>

// Pooler ragged-mean: out[b,s,:] = mean(features[b, begins[b,s]:ends[b,s], :])
// B=8, T=4096, D=256, S=1024, MAX_W=32. Empty spans -> 0.
//
// R8: gather via the global_load_lds DMA path instead of per-lane VGPR loads.
// R2-R7 established a ~15.3 B/cyc/CU L1-miss ceiling on the VGPR-load path
// (MLP-increase null, sort null, cumsum negative). m93->m97 GEMM evidence:
// the LDS-DMA path sustains ~23+ B/cyc/CU for the identical 16B/lane
// contiguous pattern. One wave per span; rolling 2x8-row (8 KB) wave-private
// LDS buffers; counted per-wave vmcnt waits; no barriers. 64 KB LDS/block
// -> 2 blocks/CU (8 waves/CU); latency hidden by deep DMA queue + consume
// overlap. XCD swizzle pins batch b -> XCD b (4 MB = one XCD L2).

#define B_DIM 8
#define T_DIM 4096
#define D_DIM 256
#define S_DIM 1024
#define MAX_W 32
#define NXCD 8

typedef float vfloat4 __attribute__((ext_vector_type(4)));
typedef const __attribute__((address_space(1))) uint32_t* gptr_t;
typedef __attribute__((address_space(3))) uint32_t* lptr_t;

__device__ __forceinline__ void wait_vmcnt_n(int n) {
    // n is wave-uniform; immediates only.
    switch (n) {
        case 0: asm volatile("s_waitcnt vmcnt(0)" ::: "memory"); break;
        case 1: asm volatile("s_waitcnt vmcnt(1)" ::: "memory"); break;
        case 2: asm volatile("s_waitcnt vmcnt(2)" ::: "memory"); break;
        case 3: asm volatile("s_waitcnt vmcnt(3)" ::: "memory"); break;
        case 4: asm volatile("s_waitcnt vmcnt(4)" ::: "memory"); break;
        case 5: asm volatile("s_waitcnt vmcnt(5)" ::: "memory"); break;
        case 6: asm volatile("s_waitcnt vmcnt(6)" ::: "memory"); break;
        case 7: asm volatile("s_waitcnt vmcnt(7)" ::: "memory"); break;
        default: asm volatile("s_waitcnt vmcnt(8)" ::: "memory"); break;
    }
}

__global__ __launch_bounds__(256) void pooler_kernel(
    const float* __restrict__ features,   // [B, T, D]
    const int*   __restrict__ begins,     // [B, S]
    const int*   __restrict__ ends,       // [B, S]
    float*       __restrict__ out)        // [B, S, D]
{
    // [wave][buf][row][chan] : 4*2*8*256*4B = 64 KB
    __shared__ float lds[4][2][8][D_DIM];

    const int phys = blockIdx.x;
    const int lblk = (phys & (NXCD - 1)) * (2048 / NXCD) + (phys >> 3);

    const int wid  = threadIdx.x >> 6;
    const int lane = threadIdx.x & 63;
    const int span = lblk * 4 + wid;                 // [0, B*S)
    const int b = span >> 10;                        // S_DIM = 1024

    int begin = begins[span];
    int end   = ends[span];
    begin = begin > 0 ? begin : 0;
    end   = end   > 0 ? end   : 0;
    end   = end   < T_DIM ? end : T_DIM;
    int w = end - begin;
    w = w < MAX_W ? w : MAX_W;

    vfloat4* outp = reinterpret_cast<vfloat4*>(out + (size_t)span * D_DIM) + lane;

    if (w <= 0) {
        vfloat4 z = {0.f, 0.f, 0.f, 0.f};
        __builtin_nontemporal_store(z, outp);
        return;
    }

    // per-lane global source: row base + lane*16B (setup guarantees
    // begin+w-1 <= T-1, so all staged rows are in-bounds)
    const float* rowbase =
        features + ((size_t)b * T_DIM + (size_t)begin) * D_DIM + lane * 4;

    // stage rows [8k, 8k+cnt) of the span into buffer k&1
    auto issue = [&](int k, int cnt) {
        const float* g = rowbase + (size_t)(8 * k) * D_DIM;
        float* lb = &lds[wid][k & 1][0][0];
        for (int j = 0; j < cnt; ++j) {
            __builtin_amdgcn_global_load_lds(
                (gptr_t)(g + (size_t)j * D_DIM),   // per-lane global src
                (lptr_t)(lb + j * D_DIM),          // wave-uniform LDS base
                16, 0, 0);                          // 16B/lane -> 1KB row
        }
    };

    vfloat4 acc = {0.f, 0.f, 0.f, 0.f};
    const int nb = (w + 7) >> 3;                     // buffers needed (1..4)

    int n0 = w > 8 ? 8 : w;
    issue(0, n0);

    for (int k = 0; k < nb; ++k) {
        int nn = 0;
        if (k + 1 < nb) {
            nn = w - 8 * (k + 1);
            nn = nn > 8 ? 8 : nn;
            issue(k + 1, nn);                        // prefetch next buffer
        }
        wait_vmcnt_n(nn);                            // buffer k complete

        const int cnt = (w - 8 * k) > 8 ? 8 : (w - 8 * k);  // wave-uniform
        const vfloat4* lp =
            reinterpret_cast<const vfloat4*>(&lds[wid][k & 1][0][0]) + lane;
        #pragma unroll
        for (int j = 0; j < 8; ++j) {
            if (j < cnt) acc += lp[(size_t)j * (D_DIM / 4)];
        }
    }

    const float inv = 1.0f / (float)w;
    vfloat4 r = acc * inv;
    __builtin_nontemporal_store(r, outp);
}

extern "C" void kernel_launch(void* const* d_in, const int* in_sizes, int n_in,
                              void* d_out, int out_size, void* d_ws, size_t ws_size,
                              hipStream_t stream) {
    const float* features = (const float*)d_in[0];
    const int*   begins   = (const int*)d_in[1];
    const int*   ends     = (const int*)d_in[2];
    float*       out      = (float*)d_out;

    const int n_spans = B_DIM * S_DIM;            // 8192
    const int blocks  = n_spans / 4;              // 4 spans (waves) per block
    pooler_kernel<<<blocks, 256, 0, stream>>>(features, begins, ends, out);
}

// Round 9
// 14.641 us; speedup vs baseline: 2.5090x; 1.5726x over previous
//
#include <hip/hip_runtime.h>
#include <hip/hip_bf16.h>

// Pooler ragged-mean: out[b,s,:] = mean(features[b, begins[b,s]:ends[b,s], :])
// B=8, T=4096, D=256, S=1024, MAX_W=32. Empty spans -> 0.
//
// R9: block-level row dedup. Spans bucket by begin>>7 (pure function, no
// sort). Block (b,r) = one per CU, 1024 threads, stages rows
// [128r, 128r+159) of batch b into 159 KB LDS ONCE via global_load_lds
// (40.7 MB total vs 135 MB logical gather = 3.3x traffic cut past the
// ~15.3 B/cyc/CU L1-miss bound of R2-R8), discovers its spans by ballot
// (thread t tests span t), then waves reduce spans from LDS and nt-store.
// XCD pin: batch b = phys%8 -> XCD b (4 MB features/batch = one XCD L2).

#define B_DIM 8
#define T_DIM 4096
#define D_DIM 256
#define S_DIM 1024
#define MAX_W 32
#define RWIDTH 128                       // begin-range width per block
#define NBLK (B_DIM * (T_DIM / RWIDTH))  // 256 blocks
#define STAGE_ROWS (RWIDTH + MAX_W - 1)  // 159 rows = 159 KB
#define CAP 508                          // span-list capacity (Poisson(32) tail << 508)

typedef float vfloat4 __attribute__((ext_vector_type(4)));
typedef const __attribute__((address_space(1))) uint32_t* gptr_t;
typedef __attribute__((address_space(3))) uint32_t* lptr_t;

struct SM {
    float rows[STAGE_ROWS][D_DIM];   // 162816 B
    int count;                       // 4 B
    unsigned short list[CAP];        // 1016 B   -> 163836 of 163840 B
};

__global__ __launch_bounds__(1024) void pooler_kernel(
    const float* __restrict__ features,   // [B, T, D]
    const int*   __restrict__ begins,     // [B, S]
    const int*   __restrict__ ends,       // [B, S]
    float*       __restrict__ out)        // [B, S, D]
{
    __shared__ SM sm;

    const int phys = blockIdx.x;
    const int b = phys & 7;          // XCD pin: batch b -> XCD b
    const int r = phys >> 3;         // 0..31 range index
    const int tid  = threadIdx.x;    // 0..1023
    const int wv   = tid >> 6;       // 0..15
    const int lane = tid & 63;

    if (tid == 0) sm.count = 0;
    __syncthreads();

    // ---- stage rows [r*128, r*128 + nrows) into LDS, once per block ----
    const int row0  = r * RWIDTH;
    const int nrows = (T_DIM - row0) < STAGE_ROWS ? (T_DIM - row0) : STAGE_ROWS;
    const float* gbase = features + ((size_t)b * T_DIM + row0) * D_DIM + lane * 4;

    #pragma unroll
    for (int c = 0; c < (STAGE_ROWS + 15) / 16; ++c) {
        const int row = c * 16 + wv;                 // wave-uniform
        if (row < nrows) {
            __builtin_amdgcn_global_load_lds(
                (gptr_t)(gbase + (size_t)row * D_DIM),   // per-lane global src
                (lptr_t)(&sm.rows[row][0]),              // wave-uniform LDS base
                16, 0, 0);                                // +lane*16 implicit
        }
    }

    // ---- discover this block's spans (thread t tests span t) ----
    {
        const int s  = tid;                          // S_DIM == 1024
        int bg = begins[b * S_DIM + s];
        int bgc = bg > 0 ? bg : 0;
        bgc = bgc < (T_DIM - 1) ? bgc : (T_DIM - 1);
        const bool pred = (bgc >> 7) == r;

        const unsigned long long mask = __ballot(pred);
        const int cnt = __popcll(mask);
        int base = 0;
        if (lane == 0 && cnt) base = atomicAdd(&sm.count, cnt);
        base = __shfl(base, 0);
        if (pred) {
            const int pos =
                base + __popcll(mask & ((1ULL << lane) - 1ULL));
            if (pos < CAP) {
                sm.list[pos] = (unsigned short)s;
            } else {
                // overflow fallback (never hit for benchmark data):
                // compute this span directly from global, scalar.
                int en = ends[b * S_DIM + s];
                int bb = bg > 0 ? bg : 0;
                en = en > 0 ? en : 0;
                en = en < T_DIM ? en : T_DIM;
                int w = en - bb;
                w = w < MAX_W ? w : MAX_W;
                float* op = out + (size_t)(b * S_DIM + s) * D_DIM;
                if (w <= 0) {
                    for (int d = 0; d < D_DIM; ++d) op[d] = 0.f;
                } else {
                    const float* fp =
                        features + ((size_t)b * T_DIM + bb) * D_DIM;
                    const float inv = 1.0f / (float)w;
                    for (int d = 0; d < D_DIM; ++d) {
                        float a = 0.f;
                        for (int j = 0; j < w; ++j) a += fp[(size_t)j * D_DIM + d];
                        op[d] = a * inv;
                    }
                }
            }
        }
    }

    __syncthreads();   // drains DMA (vmcnt 0) + makes list/count visible

    // ---- consume: one span per wave per round, reduce from LDS ----
    const int cnt = sm.count < CAP ? sm.count : CAP;
    for (int i = wv; i < cnt; i += 16) {
        const int s = sm.list[i];
        int bg = begins[b * S_DIM + s];
        int en = ends[b * S_DIM + s];
        bg = bg > 0 ? bg : 0;
        en = en > 0 ? en : 0;
        en = en < T_DIM ? en : T_DIM;
        int w = en - bg;
        w = w < MAX_W ? w : MAX_W;

        vfloat4* outp =
            reinterpret_cast<vfloat4*>(out + (size_t)(b * S_DIM + s) * D_DIM) + lane;

        if (w <= 0) {
            vfloat4 z = {0.f, 0.f, 0.f, 0.f};
            __builtin_nontemporal_store(z, outp);
            continue;
        }

        const int local = bg - row0;   // in [0, 127]; local+w-1 <= 158 staged
        const vfloat4* lp =
            reinterpret_cast<const vfloat4*>(&sm.rows[local][0]) + lane;

        vfloat4 acc = {0.f, 0.f, 0.f, 0.f};
        #pragma unroll 8
        for (int j = 0; j < w; ++j) acc += lp[(size_t)j * (D_DIM / 4)];

        const float inv = 1.0f / (float)w;
        vfloat4 res = acc * inv;
        __builtin_nontemporal_store(res, outp);
    }
}

extern "C" void kernel_launch(void* const* d_in, const int* in_sizes, int n_in,
                              void* d_out, int out_size, void* d_ws, size_t ws_size,
                              hipStream_t stream) {
    const float* features = (const float*)d_in[0];
    const int*   begins   = (const int*)d_in[1];
    const int*   ends     = (const int*)d_in[2];
    float*       out      = (float*)d_out;

    pooler_kernel<<<NBLK, 1024, 0, stream>>>(features, begins, ends, out);
}